// Round 1
// baseline (1355.745 us; speedup 1.0000x reference)
//
#include <hip/hip_runtime.h>
#include <hip/hip_bf16.h>

#define N_NODES 50000
#define N_EDGES 800000
#define DIM 128
#define TM 32  // rows per GEMM block

// ---------------------------------------------------------------------------
// GEMM1: out[i][j] = relu( sum_k A[i][k] * Q[j][k] + qb[j] )
// Block: 256 threads, 32 rows x 128 cols. Thread tile 4x4.
// Q staged transposed in LDS: Qt[k][j] (64 KB), stage writes conflict-free.
// ---------------------------------------------------------------------------
__global__ __launch_bounds__(256) void qgemm_relu(
    const float* __restrict__ A,   // [N][128]
    const float* __restrict__ Q,   // [128][128]
    const float* __restrict__ qb,  // [128]
    float* __restrict__ out, int N)
{
    __shared__ float Qt[DIM * DIM];  // Qt[k][j]
    const int tid = threadIdx.x;

    // stage Q transposed: idx -> j = idx&127 (lane-consecutive), kb = idx>>7
    for (int idx = tid; idx < DIM * DIM / 4; idx += 256) {
        const int j  = idx & 127;
        const int kb = idx >> 7;              // 0..31, k = kb*4
        const float4 q = *(const float4*)&Q[j * DIM + kb * 4];
        Qt[(kb * 4 + 0) * DIM + j] = q.x;
        Qt[(kb * 4 + 1) * DIM + j] = q.y;
        Qt[(kb * 4 + 2) * DIM + j] = q.z;
        Qt[(kb * 4 + 3) * DIM + j] = q.w;
    }
    __syncthreads();

    const int cg = tid & 31;       // col group: cols cg*4..cg*4+3
    const int rg = tid >> 5;       // row group: rows r0..r0+3
    const int r0 = blockIdx.x * TM + rg * 4;

    float acc[4][4] = {};
    for (int k = 0; k < DIM; k += 4) {
        float a_[4][4], q_[4][4];
        #pragma unroll
        for (int i = 0; i < 4; i++) {
            const int r = r0 + i;
            float4 t = make_float4(0.f, 0.f, 0.f, 0.f);
            if (r < N) t = *(const float4*)&A[(size_t)r * DIM + k];
            a_[i][0] = t.x; a_[i][1] = t.y; a_[i][2] = t.z; a_[i][3] = t.w;
        }
        #pragma unroll
        for (int kk = 0; kk < 4; kk++) {
            const float4 t = *(const float4*)&Qt[(k + kk) * DIM + cg * 4];
            q_[kk][0] = t.x; q_[kk][1] = t.y; q_[kk][2] = t.z; q_[kk][3] = t.w;
        }
        #pragma unroll
        for (int i = 0; i < 4; i++)
            #pragma unroll
            for (int j = 0; j < 4; j++)
                #pragma unroll
                for (int kk = 0; kk < 4; kk++)
                    acc[i][j] = fmaf(a_[i][kk], q_[kk][j], acc[i][j]);
    }

    const float4 b = *(const float4*)&qb[cg * 4];
    #pragma unroll
    for (int i = 0; i < 4; i++) {
        const int r = r0 + i;
        if (r >= N) continue;
        float4 o;
        o.x = fmaxf(acc[i][0] + b.x, 0.f);
        o.y = fmaxf(acc[i][1] + b.y, 0.f);
        o.z = fmaxf(acc[i][2] + b.z, 0.f);
        o.w = fmaxf(acc[i][3] + b.w, 0.f);
        *(float4*)&out[(size_t)r * DIM + cg * 4] = o;
    }
}

// ---------------------------------------------------------------------------
// Edge scatter: one 64-lane wave per edge; lane handles features {lane, lane+64}
// ---------------------------------------------------------------------------
__global__ __launch_bounds__(256) void edge_scatter(
    const float* __restrict__ n,
    const float* __restrict__ ew,
    const int* __restrict__ src,
    const int* __restrict__ dst,
    float* __restrict__ agg,
    float* __restrict__ wsum, int E)
{
    const int gid  = blockIdx.x * 256 + threadIdx.x;
    const int e    = gid >> 6;
    const int lane = gid & 63;
    if (e >= E) return;
    const int s   = src[e];
    const int d   = dst[e];
    const float w = ew[e];
    const float v0 = n[(size_t)s * DIM + lane] * w;
    const float v1 = n[(size_t)s * DIM + 64 + lane] * w;
    atomicAdd(&agg[(size_t)d * DIM + lane], v0);
    atomicAdd(&agg[(size_t)d * DIM + 64 + lane], v1);
    if (lane == 0) atomicAdd(&wsum[d], w);
}

// ---------------------------------------------------------------------------
// GEMM2 + epilogue: z = relu(concat[agg/ws, h] @ W^T + wb); out = z/||z||
// K = 256 staged as two 128-wide LDS chunks of Wt[k][j].
// ---------------------------------------------------------------------------
__global__ __launch_bounds__(256) void wgemm_norm(
    const float* __restrict__ agg,   // [N][128]
    const float* __restrict__ wsum,  // [N]
    const float* __restrict__ h,     // [N][128]
    const float* __restrict__ W,     // [128][256]
    const float* __restrict__ wb,    // [128]
    float* __restrict__ out, int N)
{
    __shared__ float Wt[DIM * DIM];  // chunk: Wt[k][j], k in [kc*128, kc*128+128)
    const int tid = threadIdx.x;
    const int cg = tid & 31;
    const int rg = tid >> 5;
    const int r0 = blockIdx.x * TM + rg * 4;

    float inv[4];
    #pragma unroll
    for (int i = 0; i < 4; i++) {
        const int r = r0 + i;
        inv[i] = (r < N) ? (1.f / fmaxf(wsum[r], 1.f)) : 0.f;
    }

    float acc[4][4] = {};
    for (int kc = 0; kc < 2; kc++) {
        __syncthreads();  // protect Wt reuse between chunks
        for (int idx = tid; idx < DIM * DIM / 4; idx += 256) {
            const int j  = idx & 127;
            const int kb = idx >> 7;
            const float4 q = *(const float4*)&W[j * 256 + kc * 128 + kb * 4];
            Wt[(kb * 4 + 0) * DIM + j] = q.x;
            Wt[(kb * 4 + 1) * DIM + j] = q.y;
            Wt[(kb * 4 + 2) * DIM + j] = q.z;
            Wt[(kb * 4 + 3) * DIM + j] = q.w;
        }
        __syncthreads();

        const float* __restrict__ Ap = (kc == 0) ? agg : h;
        for (int k = 0; k < DIM; k += 4) {
            float a_[4][4], q_[4][4];
            #pragma unroll
            for (int i = 0; i < 4; i++) {
                const int r = r0 + i;
                float4 t = make_float4(0.f, 0.f, 0.f, 0.f);
                if (r < N) t = *(const float4*)&Ap[(size_t)r * DIM + k];
                const float s = (kc == 0) ? inv[i] : 1.f;
                a_[i][0] = t.x * s; a_[i][1] = t.y * s;
                a_[i][2] = t.z * s; a_[i][3] = t.w * s;
            }
            #pragma unroll
            for (int kk = 0; kk < 4; kk++) {
                const float4 t = *(const float4*)&Wt[(k + kk) * DIM + cg * 4];
                q_[kk][0] = t.x; q_[kk][1] = t.y; q_[kk][2] = t.z; q_[kk][3] = t.w;
            }
            #pragma unroll
            for (int i = 0; i < 4; i++)
                #pragma unroll
                for (int j = 0; j < 4; j++)
                    #pragma unroll
                    for (int kk = 0; kk < 4; kk++)
                        acc[i][j] = fmaf(a_[i][kk], q_[kk][j], acc[i][j]);
        }
    }

    const float4 b = *(const float4*)&wb[cg * 4];
    #pragma unroll
    for (int i = 0; i < 4; i++) {
        const int r = r0 + i;
        float4 z;
        z.x = fmaxf(acc[i][0] + b.x, 0.f);
        z.y = fmaxf(acc[i][1] + b.y, 0.f);
        z.z = fmaxf(acc[i][2] + b.z, 0.f);
        z.w = fmaxf(acc[i][3] + b.w, 0.f);
        float ss = z.x * z.x + z.y * z.y + z.z * z.z + z.w * z.w;
        #pragma unroll
        for (int m = 1; m < 32; m <<= 1) ss += __shfl_xor(ss, m);
        float zn = sqrtf(ss);
        if (zn == 0.f) zn = 1.f;
        const float rn = 1.f / zn;
        if (r < N) {
            float4 o;
            o.x = z.x * rn; o.y = z.y * rn; o.z = z.z * rn; o.w = z.w * rn;
            *(float4*)&out[(size_t)r * DIM + cg * 4] = o;
        }
    }
}

extern "C" void kernel_launch(void* const* d_in, const int* in_sizes, int n_in,
                              void* d_out, int out_size, void* d_ws, size_t ws_size,
                              hipStream_t stream) {
    const float* h0  = (const float*)d_in[0];
    const float* ew  = (const float*)d_in[1];
    const float* Qw  = (const float*)d_in[2];
    const float* Qb  = (const float*)d_in[3];
    const float* Ww  = (const float*)d_in[4];
    const float* Wb  = (const float*)d_in[5];
    const int*  esrc = (const int*)d_in[6];
    const int*  edst = (const int*)d_in[7];
    float* out = (float*)d_out;

    float* nbuf = (float*)d_ws;
    float* agg  = nbuf + (size_t)N_NODES * DIM;
    float* wsum = agg + (size_t)N_NODES * DIM;

    const int gemm_blocks = (N_NODES + TM - 1) / TM;
    const int scat_blocks = (N_EDGES * 64) / 256;

    for (int l = 0; l < 2; l++) {
        const float* hin = (l == 0) ? h0 : out;
        hipMemsetAsync(agg, 0, (size_t)N_NODES * DIM * sizeof(float), stream);
        hipMemsetAsync(wsum, 0, (size_t)N_NODES * sizeof(float), stream);
        qgemm_relu<<<gemm_blocks, 256, 0, stream>>>(
            hin, Qw + (size_t)l * DIM * DIM, Qb + (size_t)l * DIM, nbuf, N_NODES);
        edge_scatter<<<scat_blocks, 256, 0, stream>>>(
            nbuf, ew + (size_t)l * N_EDGES, esrc + (size_t)l * N_EDGES,
            edst + (size_t)l * N_EDGES, agg, wsum, N_EDGES);
        wgemm_norm<<<gemm_blocks, 256, 0, stream>>>(
            agg, wsum, hin, Ww + (size_t)l * DIM * 2 * DIM, Wb + (size_t)l * DIM,
            out, N_NODES);
    }
}

// Round 4
// 717.651 us; speedup vs baseline: 1.8891x; 1.8891x over previous
//
#include <hip/hip_runtime.h>
#include <hip/hip_bf16.h>

#define N_NODES 50000
#define N_EDGES 800000
#define DIM 128

// ---------------------------------------------------------------------------
// Edge binning: histogram -> exclusive scan (in place) -> bin scatter.
// After bin_edges, bins[d] = end offset of bin d (start = bins[d-1] or 0).
// ---------------------------------------------------------------------------
__global__ __launch_bounds__(256) void hist_dst(
    const int* __restrict__ dst, int* __restrict__ bins, int E)
{
    const int e = blockIdx.x * 256 + threadIdx.x;
    if (e < E) atomicAdd(&bins[dst[e]], 1);
}

__global__ __launch_bounds__(1024) void scan_excl(int* __restrict__ data, int n)
{
    __shared__ int wsums[16];
    const int tid  = threadIdx.x;
    const int lane = tid & 63;
    const int wid  = tid >> 6;
    int carry = 0;
    for (int base = 0; base < n; base += 1024) {
        const int i = base + tid;
        const int x = (i < n) ? data[i] : 0;
        int v = x;
        #pragma unroll
        for (int off = 1; off < 64; off <<= 1) {
            const int t = __shfl_up(v, off);
            if (lane >= off) v += t;
        }
        if (lane == 63) wsums[wid] = v;
        __syncthreads();
        if (wid == 0 && lane < 16) {
            int s = wsums[lane];
            #pragma unroll
            for (int off = 1; off < 16; off <<= 1) {
                const int t = __shfl_up(s, off);
                if (lane >= off) s += t;
            }
            wsums[lane] = s;
        }
        __syncthreads();
        const int woff  = (wid == 0) ? 0 : wsums[wid - 1];
        const int total = wsums[15];
        if (i < n) data[i] = carry + woff + (v - x);
        carry += total;
        __syncthreads();
    }
}

__global__ __launch_bounds__(256) void bin_edges(
    const int* __restrict__ src, const int* __restrict__ dst,
    const float* __restrict__ ew, int* __restrict__ bins,
    int2* __restrict__ binned, int E)
{
    const int e = blockIdx.x * 256 + threadIdx.x;
    if (e >= E) return;
    const int d   = dst[e];
    const int pos = atomicAdd(&bins[d], 1);
    binned[pos] = make_int2(src[e], __float_as_int(ew[e]));
}

// ---------------------------------------------------------------------------
// Gather-reduce: one wave per dst node; lane handles feats {2*lane, 2*lane+1}.
// Writes agg already divided by clamp(sum_w, 1).
// ---------------------------------------------------------------------------
__global__ __launch_bounds__(256) void gather_agg(
    const float* __restrict__ nsrc, const int2* __restrict__ binned,
    const int* __restrict__ bins, float* __restrict__ agg, int N)
{
    const int lane = threadIdx.x & 63;
    const int d    = blockIdx.x * 4 + (threadIdx.x >> 6);
    if (d >= N) return;
    const int lo = (d == 0) ? 0 : bins[d - 1];
    const int hi = bins[d];
    float2 acc = make_float2(0.f, 0.f);
    float  ws  = 0.f;
    for (int p = lo; p < hi; ++p) {
        const int2 sw = binned[p];
        const float w = __int_as_float(sw.y);
        const float2 v = *(const float2*)&nsrc[(size_t)sw.x * DIM + lane * 2];
        acc.x = fmaf(v.x, w, acc.x);
        acc.y = fmaf(v.y, w, acc.y);
        ws += w;
    }
    const float inv = 1.f / fmaxf(ws, 1.f);
    float2 o; o.x = acc.x * inv; o.y = acc.y * inv;
    *(float2*)&agg[(size_t)d * DIM + lane * 2] = o;
}

// ---------------------------------------------------------------------------
// GEMM1: out = relu(A @ Q^T + qb). 32 rows x 128 cols per block, 4x4/thread.
// At (32x128) staged once; Qc[kk][j] staged per 32-wide K chunk.
// ---------------------------------------------------------------------------
__global__ __launch_bounds__(256) void qgemm_relu(
    const float* __restrict__ A, const float* __restrict__ Q,
    const float* __restrict__ qb, float* __restrict__ out, int N)
{
    __shared__ float At[32 * DIM];
    __shared__ float Qc[32 * DIM];
    const int tid = threadIdx.x;
    const int cg = tid & 31, rg = tid >> 5;
    const int r0 = blockIdx.x * 32;

    for (int f4 = tid; f4 < 1024; f4 += 256) {
        const int r = f4 >> 5, k4 = f4 & 31;
        float4 t = make_float4(0.f, 0.f, 0.f, 0.f);
        if (r0 + r < N) t = *(const float4*)&A[(size_t)(r0 + r) * DIM + k4 * 4];
        *(float4*)&At[r * DIM + k4 * 4] = t;
    }

    float acc[4][4] = {};
    for (int kc = 0; kc < 4; kc++) {
        __syncthreads();
        for (int f4 = tid; f4 < 1024; f4 += 256) {
            const int j = f4 & 127, kb = f4 >> 7;
            const float4 q = *(const float4*)&Q[j * DIM + kc * 32 + kb * 4];
            Qc[(kb * 4 + 0) * DIM + j] = q.x;
            Qc[(kb * 4 + 1) * DIM + j] = q.y;
            Qc[(kb * 4 + 2) * DIM + j] = q.z;
            Qc[(kb * 4 + 3) * DIM + j] = q.w;
        }
        __syncthreads();
        #pragma unroll
        for (int kk = 0; kk < 32; kk += 4) {
            float a_[4][4], q_[4][4];
            #pragma unroll
            for (int i = 0; i < 4; i++) {
                const float4 t = *(const float4*)&At[(rg * 4 + i) * DIM + kc * 32 + kk];
                a_[i][0] = t.x; a_[i][1] = t.y; a_[i][2] = t.z; a_[i][3] = t.w;
            }
            #pragma unroll
            for (int u = 0; u < 4; u++) {
                const float4 t = *(const float4*)&Qc[(kk + u) * DIM + cg * 4];
                q_[u][0] = t.x; q_[u][1] = t.y; q_[u][2] = t.z; q_[u][3] = t.w;
            }
            #pragma unroll
            for (int i = 0; i < 4; i++)
                #pragma unroll
                for (int j = 0; j < 4; j++)
                    #pragma unroll
                    for (int u = 0; u < 4; u++)
                        acc[i][j] = fmaf(a_[i][u], q_[u][j], acc[i][j]);
        }
    }

    const float4 b = *(const float4*)&qb[cg * 4];
    #pragma unroll
    for (int i = 0; i < 4; i++) {
        const int r = r0 + rg * 4 + i;
        if (r >= N) continue;
        float4 o;
        o.x = fmaxf(acc[i][0] + b.x, 0.f);
        o.y = fmaxf(acc[i][1] + b.y, 0.f);
        o.z = fmaxf(acc[i][2] + b.z, 0.f);
        o.w = fmaxf(acc[i][3] + b.w, 0.f);
        *(float4*)&out[(size_t)r * DIM + cg * 4] = o;
    }
}

// ---------------------------------------------------------------------------
// GEMM2 + epilogue: z = relu([agg_norm, h] @ W^T + wb); out = z / ||z||.
// agg is already divided by clamp(ws,1) in gather_agg.
// ---------------------------------------------------------------------------
__global__ __launch_bounds__(256) void wgemm_norm(
    const float* __restrict__ agg, const float* __restrict__ h,
    const float* __restrict__ W, const float* __restrict__ wb,
    float* __restrict__ out, int N)
{
    __shared__ float At[32 * DIM];
    __shared__ float Wc[32 * DIM];
    const int tid = threadIdx.x;
    const int cg = tid & 31, rg = tid >> 5;
    const int r0 = blockIdx.x * 32;

    float acc[4][4] = {};
    for (int part = 0; part < 2; part++) {
        const float* __restrict__ Ap = part ? h : agg;
        __syncthreads();
        for (int f4 = tid; f4 < 1024; f4 += 256) {
            const int r = f4 >> 5, k4 = f4 & 31;
            float4 t = make_float4(0.f, 0.f, 0.f, 0.f);
            if (r0 + r < N) t = *(const float4*)&Ap[(size_t)(r0 + r) * DIM + k4 * 4];
            *(float4*)&At[r * DIM + k4 * 4] = t;
        }
        for (int kc = 0; kc < 4; kc++) {
            __syncthreads();
            for (int f4 = tid; f4 < 1024; f4 += 256) {
                const int j = f4 & 127, kb = f4 >> 7;
                const float4 q = *(const float4*)&W[j * 256 + part * 128 + kc * 32 + kb * 4];
                Wc[(kb * 4 + 0) * DIM + j] = q.x;
                Wc[(kb * 4 + 1) * DIM + j] = q.y;
                Wc[(kb * 4 + 2) * DIM + j] = q.z;
                Wc[(kb * 4 + 3) * DIM + j] = q.w;
            }
            __syncthreads();
            #pragma unroll
            for (int kk = 0; kk < 32; kk += 4) {
                float a_[4][4], q_[4][4];
                #pragma unroll
                for (int i = 0; i < 4; i++) {
                    const float4 t = *(const float4*)&At[(rg * 4 + i) * DIM + kc * 32 + kk];
                    a_[i][0] = t.x; a_[i][1] = t.y; a_[i][2] = t.z; a_[i][3] = t.w;
                }
                #pragma unroll
                for (int u = 0; u < 4; u++) {
                    const float4 t = *(const float4*)&Wc[(kk + u) * DIM + cg * 4];
                    q_[u][0] = t.x; q_[u][1] = t.y; q_[u][2] = t.z; q_[u][3] = t.w;
                }
                #pragma unroll
                for (int i = 0; i < 4; i++)
                    #pragma unroll
                    for (int j = 0; j < 4; j++)
                        #pragma unroll
                        for (int u = 0; u < 4; u++)
                            acc[i][j] = fmaf(a_[i][u], q_[u][j], acc[i][j]);
            }
        }
    }

    const float4 b = *(const float4*)&wb[cg * 4];
    #pragma unroll
    for (int i = 0; i < 4; i++) {
        const int r = r0 + rg * 4 + i;
        float4 z;
        z.x = fmaxf(acc[i][0] + b.x, 0.f);
        z.y = fmaxf(acc[i][1] + b.y, 0.f);
        z.z = fmaxf(acc[i][2] + b.z, 0.f);
        z.w = fmaxf(acc[i][3] + b.w, 0.f);
        float ss = z.x * z.x + z.y * z.y + z.z * z.z + z.w * z.w;
        #pragma unroll
        for (int m = 1; m < 32; m <<= 1) ss += __shfl_xor(ss, m);
        float zn = sqrtf(ss);
        if (zn == 0.f) zn = 1.f;
        const float rn = 1.f / zn;
        if (r < N) {
            float4 o;
            o.x = z.x * rn; o.y = z.y * rn; o.z = z.z * rn; o.w = z.w * rn;
            *(float4*)&out[(size_t)r * DIM + cg * 4] = o;
        }
    }
}

extern "C" void kernel_launch(void* const* d_in, const int* in_sizes, int n_in,
                              void* d_out, int out_size, void* d_ws, size_t ws_size,
                              hipStream_t stream) {
    const float* h0  = (const float*)d_in[0];
    const float* ew  = (const float*)d_in[1];
    const float* Qw  = (const float*)d_in[2];
    const float* Qb  = (const float*)d_in[3];
    const float* Ww  = (const float*)d_in[4];
    const float* Wb  = (const float*)d_in[5];
    const int*  esrc = (const int*)d_in[6];
    const int*  edst = (const int*)d_in[7];
    float* out = (float*)d_out;

    float* nbuf  = (float*)d_ws;
    float* agg   = nbuf + (size_t)N_NODES * DIM;
    int*   bins  = (int*)(agg + (size_t)N_NODES * DIM);
    int2*  binned = (int2*)(bins + N_NODES);

    const int gemm_blocks = (N_NODES + 31) / 32;
    const int edge_blocks = (N_EDGES + 255) / 256;
    const int gath_blocks = (N_NODES + 3) / 4;

    for (int l = 0; l < 2; l++) {
        const float* hin = (l == 0) ? h0 : out;
        const int*   src = esrc + (size_t)l * N_EDGES;
        const int*   dst = edst + (size_t)l * N_EDGES;
        const float* w   = ew + (size_t)l * N_EDGES;

        hipMemsetAsync(bins, 0, N_NODES * sizeof(int), stream);
        hist_dst<<<edge_blocks, 256, 0, stream>>>(dst, bins, N_EDGES);
        scan_excl<<<1, 1024, 0, stream>>>(bins, N_NODES);
        bin_edges<<<edge_blocks, 256, 0, stream>>>(src, dst, w, bins, binned, N_EDGES);
        qgemm_relu<<<gemm_blocks, 256, 0, stream>>>(
            hin, Qw + (size_t)l * DIM * DIM, Qb + (size_t)l * DIM, nbuf, N_NODES);
        gather_agg<<<gath_blocks, 256, 0, stream>>>(nbuf, binned, bins, agg, N_NODES);
        wgemm_norm<<<gemm_blocks, 256, 0, stream>>>(
            agg, hin, Ww + (size_t)l * DIM * 2 * DIM, Wb + (size_t)l * DIM,
            out, N_NODES);
    }
}

// Round 6
// 621.492 us; speedup vs baseline: 2.1814x; 1.1547x over previous
//
#include <hip/hip_runtime.h>
#include <hip/hip_bf16.h>

#define N_NODES 50000
#define N_EDGES 800000
#define DIM 128
#define GROWS 64  // GEMM tile rows

// ---------------------------------------------------------------------------
// Edge binning: histogram -> parallel exclusive scan -> bin scatter.
// After bin_edges, bins[d] = end offset of bin d (start = bins[d-1] or 0).
// ---------------------------------------------------------------------------
__global__ __launch_bounds__(256) void hist_dst(
    const int* __restrict__ dst, int* __restrict__ bins, int E)
{
    const int e = blockIdx.x * 256 + threadIdx.x;
    if (e < E) atomicAdd(&bins[dst[e]], 1);
}

// Phase 1: per-256-block exclusive scan; block total -> bsums[blockIdx].
__global__ __launch_bounds__(256) void scan_blocks(
    int* __restrict__ data, int* __restrict__ bsums, int n)
{
    __shared__ int ws[4];
    const int tid = threadIdx.x, lane = tid & 63, wid = tid >> 6;
    const int i = blockIdx.x * 256 + tid;
    const int x = (i < n) ? data[i] : 0;
    int v = x;
    #pragma unroll
    for (int off = 1; off < 64; off <<= 1) {
        const int t = __shfl_up(v, off);
        if (lane >= off) v += t;
    }
    if (lane == 63) ws[wid] = v;
    __syncthreads();
    const int w0 = ws[0], w1 = ws[1], w2 = ws[2];
    const int woff = (wid > 0 ? w0 : 0) + (wid > 1 ? w1 : 0) + (wid > 2 ? w2 : 0);
    const int incl = v + woff;
    if (i < n) data[i] = incl - x;
    if (tid == 255) bsums[blockIdx.x] = incl;
}

// Phase 2: exclusive scan of block sums (single block; nb <= 256).
__global__ __launch_bounds__(256) void scan_bsums(int* __restrict__ bsums, int nb)
{
    __shared__ int ws[4];
    const int tid = threadIdx.x, lane = tid & 63, wid = tid >> 6;
    const int x = (tid < nb) ? bsums[tid] : 0;
    int v = x;
    #pragma unroll
    for (int off = 1; off < 64; off <<= 1) {
        const int t = __shfl_up(v, off);
        if (lane >= off) v += t;
    }
    if (lane == 63) ws[wid] = v;
    __syncthreads();
    const int w0 = ws[0], w1 = ws[1], w2 = ws[2];
    const int woff = (wid > 0 ? w0 : 0) + (wid > 1 ? w1 : 0) + (wid > 2 ? w2 : 0);
    if (tid < nb) bsums[tid] = (v + woff) - x;
}

// Phase 3: add scanned block offsets.
__global__ __launch_bounds__(256) void scan_add(
    int* __restrict__ data, const int* __restrict__ bsums, int n)
{
    const int i = blockIdx.x * 256 + threadIdx.x;
    if (i < n) data[i] += bsums[blockIdx.x];
}

__global__ __launch_bounds__(256) void bin_edges(
    const int* __restrict__ src, const int* __restrict__ dst,
    const float* __restrict__ ew, int* __restrict__ bins,
    int2* __restrict__ binned, int E)
{
    const int e = blockIdx.x * 256 + threadIdx.x;
    if (e >= E) return;
    const int d   = dst[e];
    const int pos = atomicAdd(&bins[d], 1);
    binned[pos] = make_int2(src[e], __float_as_int(ew[e]));
}

// ---------------------------------------------------------------------------
// Gather-reduce: one wave per dst node; lane handles feats {2*lane, 2*lane+1}.
// 2-edge unroll for memory-level parallelism. Writes agg / clamp(sum_w, 1).
// ---------------------------------------------------------------------------
__global__ __launch_bounds__(256) void gather_agg(
    const float* __restrict__ nsrc, const int2* __restrict__ binned,
    const int* __restrict__ bins, float* __restrict__ agg, int N)
{
    const int lane = threadIdx.x & 63;
    const int d    = blockIdx.x * 4 + (threadIdx.x >> 6);
    if (d >= N) return;
    const int lo = (d == 0) ? 0 : bins[d - 1];
    const int hi = bins[d];
    float2 acc = make_float2(0.f, 0.f);
    float  ws  = 0.f;
    int p = lo;
    for (; p + 1 < hi; p += 2) {
        const int2 sw0 = binned[p];
        const int2 sw1 = binned[p + 1];
        const float2 v0 = *(const float2*)&nsrc[(size_t)sw0.x * DIM + lane * 2];
        const float2 v1 = *(const float2*)&nsrc[(size_t)sw1.x * DIM + lane * 2];
        const float w0 = __int_as_float(sw0.y);
        const float w1 = __int_as_float(sw1.y);
        acc.x = fmaf(v0.x, w0, acc.x);
        acc.y = fmaf(v0.y, w0, acc.y);
        acc.x = fmaf(v1.x, w1, acc.x);
        acc.y = fmaf(v1.y, w1, acc.y);
        ws += w0 + w1;
    }
    if (p < hi) {
        const int2 sw = binned[p];
        const float w = __int_as_float(sw.y);
        const float2 v = *(const float2*)&nsrc[(size_t)sw.x * DIM + lane * 2];
        acc.x = fmaf(v.x, w, acc.x);
        acc.y = fmaf(v.y, w, acc.y);
        ws += w;
    }
    const float inv = 1.f / fmaxf(ws, 1.f);
    float2 o; o.x = acc.x * inv; o.y = acc.y * inv;
    *(float2*)&agg[(size_t)d * DIM + lane * 2] = o;
}

// ---------------------------------------------------------------------------
// GEMM1: out = relu(A @ Q^T + qb). 64 rows x 128 cols per block, 8x4/thread.
// At (64x128, 32KB) staged once; Qt[kk][j] (32x128, 16KB) per K chunk.
// ---------------------------------------------------------------------------
__global__ __launch_bounds__(256) void qgemm_relu(
    const float* __restrict__ A, const float* __restrict__ Q,
    const float* __restrict__ qb, float* __restrict__ out, int N)
{
    __shared__ float At[GROWS * DIM];
    __shared__ float Qt[32 * DIM];
    const int tid = threadIdx.x;
    const int cg = tid & 31, rg = tid >> 5;
    const int r0 = blockIdx.x * GROWS;

    for (int f4 = tid; f4 < GROWS * DIM / 4; f4 += 256) {
        const int r = f4 >> 5, k4 = f4 & 31;
        float4 t = make_float4(0.f, 0.f, 0.f, 0.f);
        if (r0 + r < N) t = *(const float4*)&A[(size_t)(r0 + r) * DIM + k4 * 4];
        *(float4*)&At[r * DIM + k4 * 4] = t;
    }

    float acc[8][4] = {};
    for (int kc = 0; kc < 4; kc++) {
        __syncthreads();
        for (int f4 = tid; f4 < 32 * DIM / 4; f4 += 256) {
            const int j = f4 & 127, kb = f4 >> 7;
            const float4 q = *(const float4*)&Q[j * DIM + kc * 32 + kb * 4];
            Qt[(kb * 4 + 0) * DIM + j] = q.x;
            Qt[(kb * 4 + 1) * DIM + j] = q.y;
            Qt[(kb * 4 + 2) * DIM + j] = q.z;
            Qt[(kb * 4 + 3) * DIM + j] = q.w;
        }
        __syncthreads();
        #pragma unroll
        for (int kk = 0; kk < 32; kk += 4) {
            float a_[8][4], q_[4][4];
            #pragma unroll
            for (int i = 0; i < 8; i++) {
                const float4 t = *(const float4*)&At[(rg * 8 + i) * DIM + kc * 32 + kk];
                a_[i][0] = t.x; a_[i][1] = t.y; a_[i][2] = t.z; a_[i][3] = t.w;
            }
            #pragma unroll
            for (int u = 0; u < 4; u++) {
                const float4 t = *(const float4*)&Qt[(kk + u) * DIM + cg * 4];
                q_[u][0] = t.x; q_[u][1] = t.y; q_[u][2] = t.z; q_[u][3] = t.w;
            }
            #pragma unroll
            for (int i = 0; i < 8; i++)
                #pragma unroll
                for (int j = 0; j < 4; j++)
                    #pragma unroll
                    for (int u = 0; u < 4; u++)
                        acc[i][j] = fmaf(a_[i][u], q_[u][j], acc[i][j]);
        }
    }

    const float4 b = *(const float4*)&qb[cg * 4];
    #pragma unroll
    for (int i = 0; i < 8; i++) {
        const int r = r0 + rg * 8 + i;
        if (r >= N) continue;
        float4 o;
        o.x = fmaxf(acc[i][0] + b.x, 0.f);
        o.y = fmaxf(acc[i][1] + b.y, 0.f);
        o.z = fmaxf(acc[i][2] + b.z, 0.f);
        o.w = fmaxf(acc[i][3] + b.w, 0.f);
        *(float4*)&out[(size_t)r * DIM + cg * 4] = o;
    }
}

// ---------------------------------------------------------------------------
// GEMM2 + epilogue: z = relu([agg_norm, h] @ W^T + wb); out = z / ||z||.
// 64x128 tile, 8x4/thread. agg pre-divided by clamp(ws,1) in gather_agg.
// ---------------------------------------------------------------------------
__global__ __launch_bounds__(256) void wgemm_norm(
    const float* __restrict__ agg, const float* __restrict__ h,
    const float* __restrict__ W, const float* __restrict__ wb,
    float* __restrict__ out, int N)
{
    __shared__ float At[GROWS * DIM];
    __shared__ float Wt[32 * DIM];
    const int tid = threadIdx.x;
    const int cg = tid & 31, rg = tid >> 5;
    const int r0 = blockIdx.x * GROWS;

    float acc[8][4] = {};
    for (int part = 0; part < 2; part++) {
        const float* __restrict__ Ap = part ? h : agg;
        __syncthreads();  // previous part's At reads done
        for (int f4 = tid; f4 < GROWS * DIM / 4; f4 += 256) {
            const int r = f4 >> 5, k4 = f4 & 31;
            float4 t = make_float4(0.f, 0.f, 0.f, 0.f);
            if (r0 + r < N) t = *(const float4*)&Ap[(size_t)(r0 + r) * DIM + k4 * 4];
            *(float4*)&At[r * DIM + k4 * 4] = t;
        }
        for (int kc = 0; kc < 4; kc++) {
            __syncthreads();
            for (int f4 = tid; f4 < 32 * DIM / 4; f4 += 256) {
                const int j = f4 & 127, kb = f4 >> 7;
                const float4 q = *(const float4*)&W[j * 256 + part * 128 + kc * 32 + kb * 4];
                Wt[(kb * 4 + 0) * DIM + j] = q.x;
                Wt[(kb * 4 + 1) * DIM + j] = q.y;
                Wt[(kb * 4 + 2) * DIM + j] = q.z;
                Wt[(kb * 4 + 3) * DIM + j] = q.w;
            }
            __syncthreads();
            #pragma unroll
            for (int kk = 0; kk < 32; kk += 4) {
                float a_[8][4], q_[4][4];
                #pragma unroll
                for (int i = 0; i < 8; i++) {
                    const float4 t = *(const float4*)&At[(rg * 8 + i) * DIM + kc * 32 + kk];
                    a_[i][0] = t.x; a_[i][1] = t.y; a_[i][2] = t.z; a_[i][3] = t.w;
                }
                #pragma unroll
                for (int u = 0; u < 4; u++) {
                    const float4 t = *(const float4*)&Wt[(kk + u) * DIM + cg * 4];
                    q_[u][0] = t.x; q_[u][1] = t.y; q_[u][2] = t.z; q_[u][3] = t.w;
                }
                #pragma unroll
                for (int i = 0; i < 8; i++)
                    #pragma unroll
                    for (int j = 0; j < 4; j++)
                        #pragma unroll
                        for (int u = 0; u < 4; u++)
                            acc[i][j] = fmaf(a_[i][u], q_[u][j], acc[i][j]);
            }
        }
    }

    const float4 b = *(const float4*)&wb[cg * 4];
    #pragma unroll
    for (int i = 0; i < 8; i++) {
        const int r = r0 + rg * 8 + i;
        float4 z;
        z.x = fmaxf(acc[i][0] + b.x, 0.f);
        z.y = fmaxf(acc[i][1] + b.y, 0.f);
        z.z = fmaxf(acc[i][2] + b.z, 0.f);
        z.w = fmaxf(acc[i][3] + b.w, 0.f);
        float ss = z.x * z.x + z.y * z.y + z.z * z.z + z.w * z.w;
        #pragma unroll
        for (int m = 1; m < 32; m <<= 1) ss += __shfl_xor(ss, m);
        float zn = sqrtf(ss);
        if (zn == 0.f) zn = 1.f;
        const float rn = 1.f / zn;
        if (r < N) {
            float4 o;
            o.x = z.x * rn; o.y = z.y * rn; o.z = z.z * rn; o.w = z.w * rn;
            *(float4*)&out[(size_t)r * DIM + cg * 4] = o;
        }
    }
}

extern "C" void kernel_launch(void* const* d_in, const int* in_sizes, int n_in,
                              void* d_out, int out_size, void* d_ws, size_t ws_size,
                              hipStream_t stream) {
    const float* h0  = (const float*)d_in[0];
    const float* ew  = (const float*)d_in[1];
    const float* Qw  = (const float*)d_in[2];
    const float* Qb  = (const float*)d_in[3];
    const float* Ww  = (const float*)d_in[4];
    const float* Wb  = (const float*)d_in[5];
    const int*  esrc = (const int*)d_in[6];
    const int*  edst = (const int*)d_in[7];
    float* out = (float*)d_out;

    float* nbuf   = (float*)d_ws;
    float* agg    = nbuf + (size_t)N_NODES * DIM;
    int*   bins   = (int*)(agg + (size_t)N_NODES * DIM);
    int2*  binned = (int2*)(bins + N_NODES);
    int*   bsums  = (int*)(binned + N_EDGES);

    const int gemm_blocks = (N_NODES + GROWS - 1) / GROWS;
    const int edge_blocks = (N_EDGES + 255) / 256;
    const int gath_blocks = (N_NODES + 3) / 4;
    const int scan_blocks_n = (N_NODES + 255) / 256;  // 196

    for (int l = 0; l < 2; l++) {
        const float* hin = (l == 0) ? h0 : out;
        const int*   src = esrc + (size_t)l * N_EDGES;
        const int*   dst = edst + (size_t)l * N_EDGES;
        const float* w   = ew + (size_t)l * N_EDGES;

        hipMemsetAsync(bins, 0, N_NODES * sizeof(int), stream);
        hist_dst<<<edge_blocks, 256, 0, stream>>>(dst, bins, N_EDGES);
        scan_blocks<<<scan_blocks_n, 256, 0, stream>>>(bins, bsums, N_NODES);
        scan_bsums<<<1, 256, 0, stream>>>(bsums, scan_blocks_n);
        scan_add<<<scan_blocks_n, 256, 0, stream>>>(bins, bsums, N_NODES);
        bin_edges<<<edge_blocks, 256, 0, stream>>>(src, dst, w, bins, binned, N_EDGES);
        qgemm_relu<<<gemm_blocks, 256, 0, stream>>>(
            hin, Qw + (size_t)l * DIM * DIM, Qb + (size_t)l * DIM, nbuf, N_NODES);
        gather_agg<<<gath_blocks, 256, 0, stream>>>(nbuf, binned, bins, agg, N_NODES);
        wgemm_norm<<<gemm_blocks, 256, 0, stream>>>(
            agg, hin, Ww + (size_t)l * DIM * 2 * DIM, Wb + (size_t)l * DIM,
            out, N_NODES);
    }
}